// Round 1
// baseline (2149.662 us; speedup 1.0000x reference)
//
#include <hip/hip_runtime.h>
#include <hip/hip_bf16.h>
#include <math.h>

#define G_   64      // B*T graphs
#define NN_  500     // nodes
#define FIN_ 32
#define HD_  128
#define C1_  256     // HEADS*HD
#define E0_  8000
#define EP_  8500    // E0 + self loops
#define TT_  16
#define NR_  2000    // B*N lstm rows

// ---------------- generic tiled fp32 GEMM: C[M,N] = A[M,K] @ B ----------------
// TRANSB=false: B is [K,N] row-major.  TRANSB=true: B is [N,K] row-major (dot of rows).
// Requires M%64==0, N%64==0, K%16==0.
template<bool TRANSB>
__global__ __launch_bounds__(256) void gemm64(
    const float* __restrict__ A, const float* __restrict__ B, float* __restrict__ C,
    int M, int N, int K, const float* __restrict__ bias1, const float* __restrict__ bias2)
{
    __shared__ float As[16][64];
    __shared__ float Bs[16][68];
    const int tid = threadIdx.x;
    const int rowb = blockIdx.y * 64;
    const int colb = blockIdx.x * 64;
    const int tr = (tid / 16) * 4;   // thread row base within tile
    const int tc = (tid % 16) * 4;   // thread col base within tile
    float acc[4][4] = {};

    for (int k0 = 0; k0 < K; k0 += 16) {
        {
            int idx = tid * 4;
            int r = idx >> 4, kk = idx & 15;
            float4 av = *(const float4*)&A[(size_t)(rowb + r) * K + k0 + kk];
            As[kk + 0][r] = av.x; As[kk + 1][r] = av.y; As[kk + 2][r] = av.z; As[kk + 3][r] = av.w;
        }
        if (TRANSB) {
            int idx = tid * 4;
            int cN = idx >> 4, kk = idx & 15;
            float4 bv = *(const float4*)&B[(size_t)(colb + cN) * K + k0 + kk];
            Bs[kk + 0][cN] = bv.x; Bs[kk + 1][cN] = bv.y; Bs[kk + 2][cN] = bv.z; Bs[kk + 3][cN] = bv.w;
        } else {
            int idx = tid * 4;
            int kk = idx >> 6, cN = idx & 63;
            float4 bv = *(const float4*)&B[(size_t)(k0 + kk) * N + colb + cN];
            *(float4*)&Bs[kk][cN] = bv;
        }
        __syncthreads();
        #pragma unroll
        for (int kk = 0; kk < 16; ++kk) {
            float4 a = *(const float4*)&As[kk][tr];
            float4 b = *(const float4*)&Bs[kk][tc];
            acc[0][0] += a.x * b.x; acc[0][1] += a.x * b.y; acc[0][2] += a.x * b.z; acc[0][3] += a.x * b.w;
            acc[1][0] += a.y * b.x; acc[1][1] += a.y * b.y; acc[1][2] += a.y * b.z; acc[1][3] += a.y * b.w;
            acc[2][0] += a.z * b.x; acc[2][1] += a.z * b.y; acc[2][2] += a.z * b.z; acc[2][3] += a.z * b.w;
            acc[3][0] += a.w * b.x; acc[3][1] += a.w * b.y; acc[3][2] += a.w * b.z; acc[3][3] += a.w * b.w;
        }
        __syncthreads();
    }
    #pragma unroll
    for (int i = 0; i < 4; ++i) {
        #pragma unroll
        for (int j = 0; j < 4; ++j) {
            int col = colb + tc + j;
            float v = acc[i][j];
            if (bias1) v += bias1[col];
            if (bias2) v += bias2[col];
            C[(size_t)(rowb + tr + i) * N + col] = v;
        }
    }
}

// ---------------- CSR build (by dst) ----------------
__global__ void k_deg(const int* __restrict__ ei, int* __restrict__ deg) {
    int e = blockIdx.x * blockDim.x + threadIdx.x;
    if (e >= EP_) return;
    int dst = e < E0_ ? ei[E0_ + e] : e - E0_;
    atomicAdd(&deg[dst], 1);
}
__global__ void k_scan(const int* __restrict__ deg, int* __restrict__ rowptr, int* __restrict__ cursor) {
    if (threadIdx.x == 0 && blockIdx.x == 0) {
        int acc = 0;
        for (int i = 0; i < NN_; ++i) { rowptr[i] = acc; cursor[i] = acc; acc += deg[i]; }
        rowptr[NN_] = acc;
    }
}
__global__ void k_fill(const int* __restrict__ ei, int* __restrict__ cursor, int* __restrict__ eids) {
    int e = blockIdx.x * blockDim.x + threadIdx.x;
    if (e >= EP_) return;
    int dst = e < E0_ ? ei[E0_ + e] : e - E0_;
    int pos = atomicAdd(&cursor[dst], 1);
    eids[pos] = e;
}

// ---------------- GATv2 edge logits ----------------
// one wave per (g, edge): logit[h] = sum_c lrelu(xl[src,h,c]+xr[dst,h,c]) * att[h,c]
template<int NH, int CD>
__global__ __launch_bounds__(256) void k_logits(
    const float* __restrict__ xl, const float* __restrict__ xr,
    const float* __restrict__ att, const int* __restrict__ ei, float* __restrict__ logits)
{
    int w = blockIdx.x * 4 + (threadIdx.x >> 6);
    int lane = threadIdx.x & 63;
    if (w >= G_ * EP_) return;
    int e = w % EP_, g = w / EP_;
    int src = e < E0_ ? ei[e] : e - E0_;
    int dst = e < E0_ ? ei[E0_ + e] : e - E0_;
    const float* pl = xl + ((size_t)g * NN_ + src) * (NH * CD);
    const float* pr = xr + ((size_t)g * NN_ + dst) * (NH * CD);
    #pragma unroll
    for (int h = 0; h < NH; ++h) {
        float s = 0.f;
        #pragma unroll
        for (int c = lane; c < CD; c += 64) {
            float v = pl[h * CD + c] + pr[h * CD + c];
            v = v > 0.f ? v : 0.2f * v;
            s += v * att[h * CD + c];
        }
        #pragma unroll
        for (int off = 32; off > 0; off >>= 1) s += __shfl_down(s, off);
        if (lane == 0) logits[((size_t)g * EP_ + e) * NH + h] = s;
    }
}

// ---------------- GATv2 aggregate (softmax over incoming edges + weighted sum) ----------------
template<int NH, int CD>
__global__ void k_aggregate(
    const float* __restrict__ xl, const float* __restrict__ logits,
    const int* __restrict__ rowptr, const int* __restrict__ eids,
    const int* __restrict__ ei, const float* __restrict__ bias, float* __restrict__ out)
{
    const int BD = NH * CD;
    int g = blockIdx.x / NN_, dst = blockIdx.x % NN_;
    int rs = rowptr[dst], re = rowptr[dst + 1];
    int tid = threadIdx.x;
    __shared__ float red[BD];
    __shared__ float mh[NH], sh[NH];
    __shared__ float exs[64 * NH];
    __shared__ int srcs[64];

    // pass 1: max per head
    for (int h = 0; h < NH; ++h) {
        float lm = -1e30f;
        for (int i = rs + tid; i < re; i += BD)
            lm = fmaxf(lm, logits[((size_t)g * EP_ + eids[i]) * NH + h]);
        red[tid] = lm; __syncthreads();
        for (int s = BD / 2; s > 0; s >>= 1) {
            if (tid < s) red[tid] = fmaxf(red[tid], red[tid + s]);
            __syncthreads();
        }
        if (tid == 0) mh[h] = red[0];
        __syncthreads();
    }
    // pass 2: sum of exp per head
    for (int h = 0; h < NH; ++h) {
        float ls = 0.f;
        for (int i = rs + tid; i < re; i += BD)
            ls += expf(logits[((size_t)g * EP_ + eids[i]) * NH + h] - mh[h]);
        red[tid] = ls; __syncthreads();
        for (int s = BD / 2; s > 0; s >>= 1) {
            if (tid < s) red[tid] += red[tid + s];
            __syncthreads();
        }
        if (tid == 0) sh[h] = red[0];
        __syncthreads();
    }
    // pass 3: weighted aggregation, chunked edge list in LDS
    int h = tid / CD, c = tid % CD;
    float acc = 0.f;
    for (int base = rs; base < re; base += 64) {
        int nl = min(64, re - base);
        __syncthreads();
        if (tid < nl) {
            int eid = eids[base + tid];
            srcs[tid] = eid < E0_ ? ei[eid] : eid - E0_;
            #pragma unroll
            for (int hh = 0; hh < NH; ++hh)
                exs[tid * NH + hh] = expf(logits[((size_t)g * EP_ + eid) * NH + hh] - mh[hh]);
        }
        __syncthreads();
        for (int i = 0; i < nl; ++i)
            acc += exs[i * NH + h] * xl[((size_t)g * NN_ + srcs[i]) * BD + h * CD + c];
    }
    out[((size_t)g * NN_ + dst) * BD + tid] = acc / (sh[h] + 1e-16f) + bias[tid];
}

// ---------------- BatchNorm (training stats over node axis) ----------------
template<int C>
__global__ void k_bnstats(const float* __restrict__ h, float* __restrict__ meanb, float* __restrict__ rstdb) {
    int g = blockIdx.x, c = threadIdx.x;
    float s = 0.f, ss = 0.f;
    for (int n = 0; n < NN_; ++n) {
        float v = h[((size_t)g * NN_ + n) * C + c];
        s += v; ss += v * v;
    }
    float m = s * (1.f / NN_);
    float var = ss * (1.f / NN_) - m * m;
    meanb[g * C + c] = m;
    rstdb[g * C + c] = rsqrtf(var + 1e-5f);
}
template<int C>
__global__ void k_bn_elu(float* __restrict__ h, const float* __restrict__ meanb,
                         const float* __restrict__ rstdb, const float* __restrict__ gamma,
                         const float* __restrict__ beta) {
    int idx = blockIdx.x * blockDim.x + threadIdx.x;
    if (idx >= G_ * NN_ * C) return;
    int c = idx % C;
    int g = idx / (NN_ * C);
    float v = (h[idx] - meanb[g * C + c]) * rstdb[g * C + c] * gamma[c] + beta[c];
    h[idx] = v > 0.f ? v : expm1f(v);
}
template<int C>
__global__ void k_bn_elu_add(const float* __restrict__ h, const float* __restrict__ meanb,
                             const float* __restrict__ rstdb, const float* __restrict__ gamma,
                             const float* __restrict__ beta, const float* __restrict__ proj,
                             float* __restrict__ outp) {
    int idx = blockIdx.x * blockDim.x + threadIdx.x;
    if (idx >= G_ * NN_ * C) return;
    int c = idx % C;
    int g = idx / (NN_ * C);
    float v = (h[idx] - meanb[g * C + c]) * rstdb[g * C + c] * gamma[c] + beta[c];
    v = v > 0.f ? v : expm1f(v);
    outp[idx] = v + proj[idx];
}

// ---------------- LSTM step: gates = h_prev @ Whh^T + xpart; fused cell update ----------------
// block: 8 rows x 512 gate cols; 256 threads
__global__ __launch_bounds__(256) void k_lstm_step(
    const float* __restrict__ hprev, const float* __restrict__ Whh,
    const float* __restrict__ xpart, int xrs,
    float* __restrict__ cbuf, float* __restrict__ hout)
{
    __shared__ float hl[8][128];
    __shared__ float wl[64][129];
    __shared__ float gl[8][512];
    int tid = threadIdx.x;
    int r0 = blockIdx.x * 8;

    for (int i = tid; i < 8 * 128; i += 256)
        hl[i >> 7][i & 127] = hprev[(size_t)(r0 + (i >> 7)) * 128 + (i & 127)];

    int col = tid & 63, rg = tid >> 6;          // wave id = rg; rows rg*2, rg*2+1
    for (int jc = 0; jc < 8; ++jc) {
        __syncthreads();
        for (int i = tid; i < 64 * 128; i += 256)
            wl[i >> 7][i & 127] = Whh[(size_t)(jc * 64 + (i >> 7)) * 128 + (i & 127)];
        __syncthreads();
        float a0 = 0.f, a1 = 0.f;
        const float* h0p = hl[rg * 2];
        const float* h1p = hl[rg * 2 + 1];
        #pragma unroll 4
        for (int k = 0; k < 128; ++k) {
            float w = wl[col][k];
            a0 += h0p[k] * w;
            a1 += h1p[k] * w;
        }
        gl[rg * 2][jc * 64 + col] = a0;
        gl[rg * 2 + 1][jc * 64 + col] = a1;
    }
    __syncthreads();
    for (int i = tid; i < 8 * 128; i += 256) {
        int r = i >> 7, k = i & 127;
        int row = r0 + r;
        const float* xp = xpart + (size_t)row * xrs;
        float gi = gl[r][k]       + xp[k];
        float gf = gl[r][128 + k] + xp[128 + k];
        float gg = gl[r][256 + k] + xp[256 + k];
        float go = gl[r][384 + k] + xp[384 + k];
        float ii = 1.f / (1.f + expf(-gi));
        float ff = 1.f / (1.f + expf(-gf));
        float g2 = tanhf(gg);
        float oo = 1.f / (1.f + expf(-go));
        float cn = ff * cbuf[(size_t)row * 128 + k] + ii * g2;
        cbuf[(size_t)row * 128 + k] = cn;
        hout[(size_t)row * 128 + k] = oo * tanhf(cn);
    }
}

// ---------------- FC head: relu(h @ W1 + b1) @ W2 + b2 ----------------
__global__ __launch_bounds__(64) void k_fc(
    const float* __restrict__ hlast, const float* __restrict__ W1, const float* __restrict__ b1,
    const float* __restrict__ W2, const float* __restrict__ b2, float* __restrict__ out)
{
    int row = blockIdx.x;
    int j = threadIdx.x;
    const float* hr = hlast + (size_t)row * 128;
    float s = b1[j];
    #pragma unroll 8
    for (int k = 0; k < 128; ++k) s += hr[k] * W1[k * 64 + j];
    s = fmaxf(s, 0.f) * W2[j];
    #pragma unroll
    for (int off = 32; off > 0; off >>= 1) s += __shfl_down(s, off);
    if (j == 0) out[row] = s + b2[0];
}

// ---------------- workspace layout (float offsets) ----------------
static const size_t OFF_XL1  = 0;          // 8,192,000   (xpart1 reuses [0, 16.384M))
static const size_t OFF_XR1  = 8192000;
static const size_t OFF_H1   = 16384000;   // 8,192,000   (xpart2 reuses [16.384M, 32.768M))
static const size_t OFF_LG1  = 24576000;   // 1,088,000
static const size_t OFF_XL2  = 25664000;   // 4,096,000
static const size_t OFF_XR2  = 29760000;   // 4,096,000
static const size_t OFF_H2   = 33856000;   // 4,096,000
static const size_t OFF_LG2  = 37952000;   //   544,000
static const size_t OFF_PRJ  = 38496000;   // 4,096,000
static const size_t OFF_HRES = 42592000;   // 4,096,000
static const size_t OFF_YS1  = 46688000;   // 4,096,000
static const size_t OFF_CB   = 50784000;   //   256,000
static const size_t OFF_H2B  = 51040000;   //   256,000
static const size_t OFF_H0   = 51296000;   //   256,000
static const size_t OFF_STAT = 51552000;   // mean1 16384 | rstd1 16384 | mean2 8192 | rstd2 8192
static const size_t OFF_INT  = 51601152;   // int region

extern "C" void kernel_launch(void* const* d_in, const int* in_sizes, int n_in,
                              void* d_out, int out_size, void* d_ws, size_t ws_size,
                              hipStream_t stream) {
    const float* x        = (const float*)d_in[0];
    const int*   ei       = (const int*)  d_in[1];
    const float* W_proj   = (const float*)d_in[2];
    const float* b_proj   = (const float*)d_in[3];
    const float* gat1_Wl  = (const float*)d_in[4];
    const float* gat1_Wr  = (const float*)d_in[5];
    const float* gat1_att = (const float*)d_in[6];
    const float* gat1_b   = (const float*)d_in[7];
    const float* bn1_g    = (const float*)d_in[8];
    const float* bn1_b    = (const float*)d_in[9];
    const float* gat2_Wl  = (const float*)d_in[10];
    const float* gat2_Wr  = (const float*)d_in[11];
    const float* gat2_att = (const float*)d_in[12];
    const float* gat2_b   = (const float*)d_in[13];
    const float* bn2_g    = (const float*)d_in[14];
    const float* bn2_b    = (const float*)d_in[15];
    const float* Wih0     = (const float*)d_in[16];
    const float* Whh0     = (const float*)d_in[17];
    const float* bih0     = (const float*)d_in[18];
    const float* bhh0     = (const float*)d_in[19];
    const float* Wih1     = (const float*)d_in[20];
    const float* Whh1     = (const float*)d_in[21];
    const float* bih1     = (const float*)d_in[22];
    const float* bhh1     = (const float*)d_in[23];
    const float* fc_W1    = (const float*)d_in[24];
    const float* fc_b1    = (const float*)d_in[25];
    const float* fc_W2    = (const float*)d_in[26];
    const float* fc_b2    = (const float*)d_in[27];
    float* out = (float*)d_out;

    float* ws = (float*)d_ws;
    float* xl1   = ws + OFF_XL1;
    float* xr1   = ws + OFF_XR1;
    float* h1    = ws + OFF_H1;
    float* lg1   = ws + OFF_LG1;
    float* xl2   = ws + OFF_XL2;
    float* xr2   = ws + OFF_XR2;
    float* h2    = ws + OFF_H2;
    float* lg2   = ws + OFF_LG2;
    float* proj  = ws + OFF_PRJ;
    float* hres  = ws + OFF_HRES;
    float* ys1   = ws + OFF_YS1;
    float* cbuf  = ws + OFF_CB;
    float* h2b   = ws + OFF_H2B;
    float* h0z   = ws + OFF_H0;
    float* mean1 = ws + OFF_STAT;
    float* rstd1 = mean1 + 16384;
    float* mean2 = rstd1 + 16384;
    float* rstd2 = mean2 + 8192;
    float* xpart1 = ws + OFF_XL1;  // reuse xl1+xr1 region (16.384M floats)
    float* xpart2 = ws + OFF_H1;   // reuse h1..xr2 region (16.384M floats)

    int* ibase  = (int*)(ws + OFF_INT);
    int* deg    = ibase;
    int* rowptr = ibase + 512;
    int* cursor = ibase + 1024;
    int* eids   = ibase + 1536;

    // ---- CSR build ----
    hipMemsetAsync(deg, 0, NN_ * sizeof(int), stream);
    hipMemsetAsync(h0z, 0, NR_ * HD_ * sizeof(float), stream);
    hipMemsetAsync(cbuf, 0, NR_ * HD_ * sizeof(float), stream);
    k_deg<<<(EP_ + 255) / 256, 256, 0, stream>>>(ei, deg);
    k_scan<<<1, 1, 0, stream>>>(deg, rowptr, cursor);
    k_fill<<<(EP_ + 255) / 256, 256, 0, stream>>>(ei, cursor, eids);

    // ---- GAT1 ----
    gemm64<false><<<dim3(C1_ / 64, 32000 / 64), 256, 0, stream>>>(x, gat1_Wl, xl1, 32000, C1_, FIN_, nullptr, nullptr);
    gemm64<false><<<dim3(C1_ / 64, 32000 / 64), 256, 0, stream>>>(x, gat1_Wr, xr1, 32000, C1_, FIN_, nullptr, nullptr);
    k_logits<2, HD_><<<(G_ * EP_ + 3) / 4, 256, 0, stream>>>(xl1, xr1, gat1_att, ei, lg1);
    k_aggregate<2, HD_><<<G_ * NN_, 256, 0, stream>>>(xl1, lg1, rowptr, eids, ei, gat1_b, h1);
    k_bnstats<C1_><<<G_, C1_, 0, stream>>>(h1, mean1, rstd1);
    k_bn_elu<C1_><<<(G_ * NN_ * C1_ + 255) / 256, 256, 0, stream>>>(h1, mean1, rstd1, bn1_g, bn1_b);

    // ---- GAT2 ----
    gemm64<false><<<dim3(HD_ / 64, 32000 / 64), 256, 0, stream>>>(h1, gat2_Wl, xl2, 32000, HD_, C1_, nullptr, nullptr);
    gemm64<false><<<dim3(HD_ / 64, 32000 / 64), 256, 0, stream>>>(h1, gat2_Wr, xr2, 32000, HD_, C1_, nullptr, nullptr);
    k_logits<1, HD_><<<(G_ * EP_ + 3) / 4, 256, 0, stream>>>(xl2, xr2, gat2_att, ei, lg2);
    k_aggregate<1, HD_><<<G_ * NN_, 128, 0, stream>>>(xl2, lg2, rowptr, eids, ei, gat2_b, h2);
    k_bnstats<HD_><<<G_, HD_, 0, stream>>>(h2, mean2, rstd2);

    // ---- residual projection + BN2/ELU/add ----
    gemm64<false><<<dim3(HD_ / 64, 32000 / 64), 256, 0, stream>>>(x, W_proj, proj, 32000, HD_, FIN_, b_proj, nullptr);
    k_bn_elu_add<HD_><<<(G_ * NN_ * HD_ + 255) / 256, 256, 0, stream>>>(h2, mean2, rstd2, bn2_g, bn2_b, proj, hres);

    // ---- LSTM layer 1 ----
    // xpart1[r, j] for r = i*16 + t  (hres viewed as [32000,128])
    gemm64<true><<<dim3(512 / 64, 32000 / 64), 256, 0, stream>>>(hres, Wih0, xpart1, 32000, 512, HD_, bih0, bhh0);
    for (int t = 0; t < TT_; ++t) {
        const float* hprev = (t == 0) ? h0z : (ys1 + (size_t)(t - 1) * NR_ * HD_);
        k_lstm_step<<<NR_ / 8, 256, 0, stream>>>(hprev, Whh0, xpart1 + (size_t)t * 512, 16 * 512,
                                                 cbuf, ys1 + (size_t)t * NR_ * HD_);
    }

    // ---- LSTM layer 2 ----
    gemm64<true><<<dim3(512 / 64, 32000 / 64), 256, 0, stream>>>(ys1, Wih1, xpart2, 32000, 512, HD_, bih1, bhh1);
    hipMemsetAsync(cbuf, 0, NR_ * HD_ * sizeof(float), stream);
    for (int t = 0; t < TT_; ++t) {
        const float* hprev = (t == 0) ? h0z : h2b;
        k_lstm_step<<<NR_ / 8, 256, 0, stream>>>(hprev, Whh1, xpart2 + (size_t)t * NR_ * 512, 512,
                                                 cbuf, h2b);
    }

    // ---- FC head ----
    k_fc<<<NR_, 64, 0, stream>>>(h2b, fc_W1, fc_b1, fc_W2, fc_b2, out);
}

// Round 2
// 1012.503 us; speedup vs baseline: 2.1231x; 2.1231x over previous
//
#include <hip/hip_runtime.h>
#include <hip/hip_bf16.h>
#include <math.h>

#define G_   64      // B*T graphs
#define NN_  500     // nodes
#define FIN_ 32
#define HD_  128
#define C1_  256     // HEADS*HD
#define E0_  8000
#define EP_  8500    // E0 + self loops
#define TT_  16
#define NR_  2000    // B*N lstm rows

// ---------------- tiled fp32 GEMM: C[M,N] = A[M,K] @ B[K,N] (+bias1+bias2) ----------------
// Requires M%128==0, N%128==0, K%32==0.
__global__ __launch_bounds__(256) void gemm128(
    const float* __restrict__ A, const float* __restrict__ B, float* __restrict__ C,
    int M, int N, int K, const float* __restrict__ bias1, const float* __restrict__ bias2)
{
    __shared__ float As[32][128];
    __shared__ float Bs[32][132];
    const int tid = threadIdx.x;
    const int rowb = blockIdx.y * 128;
    const int colb = blockIdx.x * 128;
    const int ra = (tid / 16) * 4;   // row base (plus +64 group)
    const int cb = (tid % 16) * 4;   // col base (plus +64 group)
    float acc[8][8] = {};

    const int ar = tid >> 1;            // 0..127  (A staging row)
    const int ak = (tid & 1) * 16;      // 0 or 16 (A staging k base)
    const int bk = tid >> 3;            // 0..31   (B staging k row)
    const int bc = (tid & 7) * 16;      // B staging col base

    for (int k0 = 0; k0 < K; k0 += 32) {
        {
            const float* ap = &A[(size_t)(rowb + ar) * K + k0 + ak];
            float4 v0 = *(const float4*)(ap);
            float4 v1 = *(const float4*)(ap + 4);
            float4 v2 = *(const float4*)(ap + 8);
            float4 v3 = *(const float4*)(ap + 12);
            As[ak+ 0][ar]=v0.x; As[ak+ 1][ar]=v0.y; As[ak+ 2][ar]=v0.z; As[ak+ 3][ar]=v0.w;
            As[ak+ 4][ar]=v1.x; As[ak+ 5][ar]=v1.y; As[ak+ 6][ar]=v1.z; As[ak+ 7][ar]=v1.w;
            As[ak+ 8][ar]=v2.x; As[ak+ 9][ar]=v2.y; As[ak+10][ar]=v2.z; As[ak+11][ar]=v2.w;
            As[ak+12][ar]=v3.x; As[ak+13][ar]=v3.y; As[ak+14][ar]=v3.z; As[ak+15][ar]=v3.w;
        }
        {
            const float* bp = &B[(size_t)(k0 + bk) * N + colb + bc];
            *(float4*)&Bs[bk][bc]    = *(const float4*)(bp);
            *(float4*)&Bs[bk][bc+4]  = *(const float4*)(bp+4);
            *(float4*)&Bs[bk][bc+8]  = *(const float4*)(bp+8);
            *(float4*)&Bs[bk][bc+12] = *(const float4*)(bp+12);
        }
        __syncthreads();
        #pragma unroll
        for (int kk = 0; kk < 32; ++kk) {
            float4 a0 = *(const float4*)&As[kk][ra];
            float4 a1 = *(const float4*)&As[kk][ra+64];
            float4 b0 = *(const float4*)&Bs[kk][cb];
            float4 b1 = *(const float4*)&Bs[kk][cb+64];
            float av[8] = {a0.x,a0.y,a0.z,a0.w,a1.x,a1.y,a1.z,a1.w};
            float bv[8] = {b0.x,b0.y,b0.z,b0.w,b1.x,b1.y,b1.z,b1.w};
            #pragma unroll
            for (int i = 0; i < 8; ++i)
                #pragma unroll
                for (int j = 0; j < 8; ++j)
                    acc[i][j] += av[i] * bv[j];
        }
        __syncthreads();
    }
    #pragma unroll
    for (int i = 0; i < 8; ++i) {
        int rloc = ra + (i & 3) + (i >> 2) * 64;
        #pragma unroll
        for (int jg = 0; jg < 2; ++jg) {
            #pragma unroll
            for (int j = 0; j < 4; ++j) {
                int col = colb + cb + jg * 64 + j;
                float v = acc[i][jg*4+j];
                if (bias1) v += bias1[col];
                if (bias2) v += bias2[col];
                C[(size_t)(rowb + rloc) * N + col] = v;
            }
        }
    }
}

// ---------------- CSR build (by dst) ----------------
__global__ void k_deg(const int* __restrict__ ei, int* __restrict__ deg) {
    int e = blockIdx.x * blockDim.x + threadIdx.x;
    if (e >= EP_) return;
    int dst = e < E0_ ? ei[E0_ + e] : e - E0_;
    atomicAdd(&deg[dst], 1);
}
__global__ void k_scan(const int* __restrict__ deg, int* __restrict__ rowptr, int* __restrict__ cursor) {
    if (threadIdx.x == 0 && blockIdx.x == 0) {
        int acc = 0;
        for (int i = 0; i < NN_; ++i) { rowptr[i] = acc; cursor[i] = acc; acc += deg[i]; }
        rowptr[NN_] = acc;
    }
}
__global__ void k_fill(const int* __restrict__ ei, int* __restrict__ cursor, int* __restrict__ eids) {
    int e = blockIdx.x * blockDim.x + threadIdx.x;
    if (e >= EP_) return;
    int dst = e < E0_ ? ei[E0_ + e] : e - E0_;
    int pos = atomicAdd(&cursor[dst], 1);
    eids[pos] = e;
}

// ---------------- fused GATv2: logits + online softmax + aggregate ----------------
// one block per (g, dst); BD = NH*CD threads.
template<int NH, int CD>
__global__ void k_gat(const float* __restrict__ xl, const float* __restrict__ xr,
                      const float* __restrict__ att, const int* __restrict__ ei,
                      const int* __restrict__ rowptr, const int* __restrict__ eids,
                      const float* __restrict__ bias, float* __restrict__ out)
{
    const int BD = NH * CD;
    const int NW = BD / 64;
    int g = blockIdx.x / NN_, dst = blockIdx.x % NN_;
    int tid = threadIdx.x, lane = tid & 63, w = tid >> 6;
    int h = tid / CD;
    int rs = rowptr[dst], re = rowptr[dst + 1];
    __shared__ float xrs[BD], atts[BD];
    __shared__ float exl[64][NH];
    __shared__ int   srcs[64];
    __shared__ float fct[NH], mrun_s[NH], srun_s[NH];
    size_t gbase = (size_t)g * NN_;
    xrs[tid]  = xr[(gbase + dst) * BD + tid];
    atts[tid] = att[tid];
    if (tid < NH) { mrun_s[tid] = -1e30f; srun_s[tid] = 0.f; }
    float acc = 0.f;
    for (int base = rs; base < re; base += 64) {
        int nl = min(64, re - base);
        __syncthreads();                 // protects srcs/exl reuse + first-iter init
        if (tid < nl) {
            int eid = eids[base + tid];
            srcs[tid] = eid < E0_ ? ei[eid] : eid - E0_;
        }
        __syncthreads();
        // logits: each wave handles edges i = w, w+NW, ...
        for (int i = w; i < nl; i += NW) {
            const float* pl = &xl[(gbase + srcs[i]) * BD];
            #pragma unroll
            for (int hh = 0; hh < NH; ++hh) {
                float s = 0.f;
                #pragma unroll
                for (int c = lane; c < CD; c += 64) {
                    float v = pl[hh*CD + c] + xrs[hh*CD + c];
                    v = v > 0.f ? v : 0.2f * v;
                    s += v * atts[hh*CD + c];
                }
                #pragma unroll
                for (int o = 32; o; o >>= 1) s += __shfl_down(s, o);
                if (lane == 0) exl[i][hh] = s;
            }
        }
        __syncthreads();
        // wave 0: online-softmax bookkeeping for this chunk
        if (w == 0) {
            #pragma unroll
            for (int hh = 0; hh < NH; ++hh) {
                float v = lane < nl ? exl[lane][hh] : -1e30f;
                float mx = v;
                #pragma unroll
                for (int o = 32; o; o >>= 1) mx = fmaxf(mx, __shfl_xor(mx, o));
                float nm = fmaxf(mrun_s[hh], mx);
                float e = lane < nl ? __expf(v - nm) : 0.f;
                if (lane < nl) exl[lane][hh] = e;
                float sm = e;
                #pragma unroll
                for (int o = 32; o; o >>= 1) sm += __shfl_xor(sm, o);
                if (lane == 0) {
                    float f = __expf(mrun_s[hh] - nm);
                    fct[hh] = f;
                    srun_s[hh] = srun_s[hh] * f + sm;
                    mrun_s[hh] = nm;
                }
            }
        }
        __syncthreads();
        acc *= fct[h];
        for (int i = 0; i < nl; ++i)
            acc += exl[i][h] * xl[(gbase + srcs[i]) * BD + tid];
    }
    out[(gbase + dst) * BD + tid] = acc / (srun_s[h] + 1e-16f) + bias[tid];
}

// ---------------- BatchNorm (training stats over node axis) ----------------
template<int C>
__global__ void k_bnstats(const float* __restrict__ h, float* __restrict__ meanb, float* __restrict__ rstdb) {
    int g = blockIdx.x, c = threadIdx.x;
    float s = 0.f, ss = 0.f;
    for (int n = 0; n < NN_; ++n) {
        float v = h[((size_t)g * NN_ + n) * C + c];
        s += v; ss += v * v;
    }
    float m = s * (1.f / NN_);
    float var = ss * (1.f / NN_) - m * m;
    meanb[g * C + c] = m;
    rstdb[g * C + c] = rsqrtf(var + 1e-5f);
}
template<int C>
__global__ void k_bn_elu(float* __restrict__ h, const float* __restrict__ meanb,
                         const float* __restrict__ rstdb, const float* __restrict__ gamma,
                         const float* __restrict__ beta) {
    int idx = blockIdx.x * blockDim.x + threadIdx.x;
    if (idx >= G_ * NN_ * C) return;
    int c = idx % C;
    int g = idx / (NN_ * C);
    float v = (h[idx] - meanb[g * C + c]) * rstdb[g * C + c] * gamma[c] + beta[c];
    h[idx] = v > 0.f ? v : expm1f(v);
}
template<int C>
__global__ void k_bn_elu_add(const float* __restrict__ h, const float* __restrict__ meanb,
                             const float* __restrict__ rstdb, const float* __restrict__ gamma,
                             const float* __restrict__ beta, const float* __restrict__ proj,
                             float* __restrict__ outp) {
    int idx = blockIdx.x * blockDim.x + threadIdx.x;
    if (idx >= G_ * NN_ * C) return;
    int c = idx % C;
    int g = idx / (NN_ * C);
    float v = (h[idx] - meanb[g * C + c]) * rstdb[g * C + c] * gamma[c] + beta[c];
    v = v > 0.f ? v : expm1f(v);
    outp[idx] = v + proj[idx];
}

// ---------------- fused LSTM step (both layers in one launch) ----------------
// gates = hprev @ Whh^T + xin_row @ Wih^T + bih + bhh ; fused cell update.
// Per side: 125 blocks x (16 rows x 512 gate cols), 256 threads.
__device__ __forceinline__ float fsig(float x)  { return 1.f / (1.f + __expf(-x)); }
__device__ __forceinline__ float ftanh(float x) {
    float e = __expf(fminf(fmaxf(2.f * x, -30.f), 30.f));
    return (e - 1.f) / (e + 1.f);
}

__global__ __launch_bounds__(256) void k_lstm_dual(
    const float* __restrict__ hpA, const float* __restrict__ WhhA, const float* __restrict__ WihA,
    const float* __restrict__ xinA, size_t rsA, const float* __restrict__ bihA, const float* __restrict__ bhhA,
    float* __restrict__ cbA, float* __restrict__ hoA, int actA,
    const float* __restrict__ hpB, const float* __restrict__ WhhB, const float* __restrict__ WihB,
    const float* __restrict__ xinB, size_t rsB, const float* __restrict__ bihB, const float* __restrict__ bhhB,
    float* __restrict__ cbB, float* __restrict__ hoB, int actB)
{
    __shared__ float As[16][16];
    __shared__ float Bs[16][512];
    int blk = blockIdx.x;
    const float* hprev; const float* Whh; const float* Wih; const float* xin; size_t rs;
    const float* bih; const float* bhh; float* cb; float* ho; int r0;
    if (blk < 125) {
        if (!actA) return;
        hprev = hpA; Whh = WhhA; Wih = WihA; xin = xinA; rs = rsA;
        bih = bihA; bhh = bhhA; cb = cbA; ho = hoA; r0 = blk * 16;
    } else {
        if (!actB) return;
        hprev = hpB; Whh = WhhB; Wih = WihB; xin = xinB; rs = rsB;
        bih = bihB; bhh = bhhB; cb = cbB; ho = hoB; r0 = (blk - 125) * 16;
    }
    const int tid = threadIdx.x, lane = tid & 63, w = tid >> 6;
    const int sr = tid >> 4, sk = tid & 15;   // A staging: row sr, k sk
    const int bn0 = tid * 2;                  // B staging: weight rows bn0, bn0+1
    float acc0[4][4] = {}, acc1[4][4] = {};

    float  a_st;
    float4 u0[4], u1[4];
    // prologue: load chunk 0
    {
        const float* asrc = hprev; const float* wsrc = Whh;
        a_st = asrc[(size_t)(r0 + sr) * 128 + sk];
        const float* p0 = &wsrc[(size_t)bn0 * 128];
        const float* p1 = p0 + 128;
        u0[0] = *(const float4*)(p0);    u0[1] = *(const float4*)(p0+4);
        u0[2] = *(const float4*)(p0+8);  u0[3] = *(const float4*)(p0+12);
        u1[0] = *(const float4*)(p1);    u1[1] = *(const float4*)(p1+4);
        u1[2] = *(const float4*)(p1+8);  u1[3] = *(const float4*)(p1+12);
    }
    for (int c = 0; c < 16; ++c) {
        // store staged chunk to LDS
        As[sk][sr] = a_st;
        #pragma unroll
        for (int q = 0; q < 4; ++q) {
            Bs[q*4+0][bn0] = u0[q].x; Bs[q*4+1][bn0] = u0[q].y;
            Bs[q*4+2][bn0] = u0[q].z; Bs[q*4+3][bn0] = u0[q].w;
            Bs[q*4+0][bn0+1] = u1[q].x; Bs[q*4+1][bn0+1] = u1[q].y;
            Bs[q*4+2][bn0+1] = u1[q].z; Bs[q*4+3][bn0+1] = u1[q].w;
        }
        __syncthreads();
        // issue next chunk's global loads (latency hidden under compute)
        if (c < 15) {
            int k0 = (c + 1) * 16;
            const float* asrc; const float* wsrc; int kof; size_t ars;
            if (k0 < 128) { asrc = hprev; wsrc = Whh; kof = k0; ars = 128; }
            else          { asrc = xin;   wsrc = Wih; kof = k0 - 128; ars = rs; }
            a_st = asrc[(size_t)(r0 + sr) * ars + kof + sk];
            const float* p0 = &wsrc[(size_t)bn0 * 128 + kof];
            const float* p1 = p0 + 128;
            u0[0] = *(const float4*)(p0);    u0[1] = *(const float4*)(p0+4);
            u0[2] = *(const float4*)(p0+8);  u0[3] = *(const float4*)(p0+12);
            u1[0] = *(const float4*)(p1);    u1[1] = *(const float4*)(p1+4);
            u1[2] = *(const float4*)(p1+8);  u1[3] = *(const float4*)(p1+12);
        }
        // compute on current LDS contents
        #pragma unroll
        for (int kk = 0; kk < 16; ++kk) {
            float4 a  = *(const float4*)&As[kk][w*4];
            float4 b0 = *(const float4*)&Bs[kk][lane*4];
            float4 b1 = *(const float4*)&Bs[kk][lane*4 + 256];
            float aw[4] = {a.x, a.y, a.z, a.w};
            float bw0[4] = {b0.x, b0.y, b0.z, b0.w};
            float bw1[4] = {b1.x, b1.y, b1.z, b1.w};
            #pragma unroll
            for (int r = 0; r < 4; ++r)
                #pragma unroll
                for (int j = 0; j < 4; ++j) {
                    acc0[r][j] += aw[r] * bw0[j];
                    acc1[r][j] += aw[r] * bw1[j];
                }
        }
        __syncthreads();
    }
    // epilogue: lane L<32 holds gates i (cols L*4+j) and g (256+L*4+j);
    // partner lane L+32 holds f (128+L*4+j) and o (384+L*4+j).
    float4 bi0 = *(const float4*)&bih[lane*4];
    float4 bh0 = *(const float4*)&bhh[lane*4];
    float4 bi1 = *(const float4*)&bih[lane*4 + 256];
    float4 bh1 = *(const float4*)&bhh[lane*4 + 256];
    const float* bi0f = (const float*)&bi0; const float* bh0f = (const float*)&bh0;
    const float* bi1f = (const float*)&bi1; const float* bh1f = (const float*)&bh1;
    int kcol = (lane & 31) * 4;
    #pragma unroll
    for (int r = 0; r < 4; ++r) {
        size_t row = (size_t)r0 + w * 4 + r;
        float g0[4], g1[4];
        #pragma unroll
        for (int j = 0; j < 4; ++j) {
            g0[j] = acc0[r][j] + bi0f[j] + bh0f[j];
            g1[j] = acc1[r][j] + bi1f[j] + bh1f[j];
        }
        float p0[4], p1[4];
        #pragma unroll
        for (int j = 0; j < 4; ++j) {
            p0[j] = __shfl_xor(g0[j], 32);
            p1[j] = __shfl_xor(g1[j], 32);
        }
        if (lane < 32) {
            float4 cold = *(const float4*)&cb[row * 128 + kcol];
            const float* cf = (const float*)&cold;
            float cv[4], hv[4];
            #pragma unroll
            for (int j = 0; j < 4; ++j) {
                float iv = fsig(g0[j]);
                float gv = ftanh(g1[j]);
                float fv = fsig(p0[j]);
                float ov = fsig(p1[j]);
                float cn = fv * cf[j] + iv * gv;
                cv[j] = cn;
                hv[j] = ov * ftanh(cn);
            }
            *(float4*)&cb[row * 128 + kcol] = make_float4(cv[0], cv[1], cv[2], cv[3]);
            *(float4*)&ho[row * 128 + kcol] = make_float4(hv[0], hv[1], hv[2], hv[3]);
        }
    }
}

// ---------------- FC head: relu(h @ W1 + b1) @ W2 + b2 ----------------
__global__ __launch_bounds__(64) void k_fc(
    const float* __restrict__ hlast, const float* __restrict__ W1, const float* __restrict__ b1,
    const float* __restrict__ W2, const float* __restrict__ b2, float* __restrict__ out)
{
    int row = blockIdx.x;
    int j = threadIdx.x;
    const float* hr = hlast + (size_t)row * 128;
    float s = b1[j];
    #pragma unroll 8
    for (int k = 0; k < 128; ++k) s += hr[k] * W1[k * 64 + j];
    s = fmaxf(s, 0.f) * W2[j];
    #pragma unroll
    for (int off = 32; off > 0; off >>= 1) s += __shfl_down(s, off);
    if (j == 0) out[row] = s + b2[0];
}

// ---------------- workspace layout (float offsets) ----------------
static const size_t OFF_XL1  = 0;           // 8,192,000
static const size_t OFF_XR1  = 8192000;     // 8,192,000
static const size_t OFF_H1   = 16384000;    // 8,192,000
static const size_t OFF_XL2  = 24576000;    // 4,096,000
static const size_t OFF_XR2  = 28672000;    // 4,096,000
static const size_t OFF_H2   = 32768000;    // 4,096,000
static const size_t OFF_PRJ  = 36864000;    // 4,096,000
static const size_t OFF_HRES = 40960000;    // 4,096,000
static const size_t OFF_YS1  = 45056000;    // 4,096,000
static const size_t OFF_CB1  = 49152000;    //   256,000
static const size_t OFF_CB2  = 49408000;    //   256,000
static const size_t OFF_H2B  = 49664000;    //   256,000
static const size_t OFF_H0   = 49920000;    //   256,000
static const size_t OFF_STAT = 50176000;    // mean1/rstd1 16384 ea, mean2/rstd2 8192 ea
static const size_t OFF_INT  = 50225152;    // int region

extern "C" void kernel_launch(void* const* d_in, const int* in_sizes, int n_in,
                              void* d_out, int out_size, void* d_ws, size_t ws_size,
                              hipStream_t stream) {
    const float* x        = (const float*)d_in[0];
    const int*   ei       = (const int*)  d_in[1];
    const float* W_proj   = (const float*)d_in[2];
    const float* b_proj   = (const float*)d_in[3];
    const float* gat1_Wl  = (const float*)d_in[4];
    const float* gat1_Wr  = (const float*)d_in[5];
    const float* gat1_att = (const float*)d_in[6];
    const float* gat1_b   = (const float*)d_in[7];
    const float* bn1_g    = (const float*)d_in[8];
    const float* bn1_b    = (const float*)d_in[9];
    const float* gat2_Wl  = (const float*)d_in[10];
    const float* gat2_Wr  = (const float*)d_in[11];
    const float* gat2_att = (const float*)d_in[12];
    const float* gat2_b   = (const float*)d_in[13];
    const float* bn2_g    = (const float*)d_in[14];
    const float* bn2_b    = (const float*)d_in[15];
    const float* Wih0     = (const float*)d_in[16];
    const float* Whh0     = (const float*)d_in[17];
    const float* bih0     = (const float*)d_in[18];
    const float* bhh0     = (const float*)d_in[19];
    const float* Wih1     = (const float*)d_in[20];
    const float* Whh1     = (const float*)d_in[21];
    const float* bih1     = (const float*)d_in[22];
    const float* bhh1     = (const float*)d_in[23];
    const float* fc_W1    = (const float*)d_in[24];
    const float* fc_b1    = (const float*)d_in[25];
    const float* fc_W2    = (const float*)d_in[26];
    const float* fc_b2    = (const float*)d_in[27];
    float* out = (float*)d_out;

    float* ws = (float*)d_ws;
    float* xl1   = ws + OFF_XL1;
    float* xr1   = ws + OFF_XR1;
    float* h1    = ws + OFF_H1;
    float* xl2   = ws + OFF_XL2;
    float* xr2   = ws + OFF_XR2;
    float* h2    = ws + OFF_H2;
    float* proj  = ws + OFF_PRJ;
    float* hres  = ws + OFF_HRES;
    float* ys1   = ws + OFF_YS1;
    float* cb1   = ws + OFF_CB1;
    float* cb2   = ws + OFF_CB2;
    float* h2b   = ws + OFF_H2B;
    float* h0z   = ws + OFF_H0;
    float* mean1 = ws + OFF_STAT;
    float* rstd1 = mean1 + 16384;
    float* mean2 = rstd1 + 16384;
    float* rstd2 = mean2 + 8192;

    int* ibase  = (int*)(ws + OFF_INT);
    int* deg    = ibase;
    int* rowptr = ibase + 512;
    int* cursor = ibase + 1024;
    int* eids   = ibase + 1536;

    // ---- init + CSR build ----
    hipMemsetAsync(deg, 0, NN_ * sizeof(int), stream);
    hipMemsetAsync(h0z, 0, NR_ * HD_ * sizeof(float), stream);
    hipMemsetAsync(cb1, 0, NR_ * HD_ * sizeof(float), stream);
    hipMemsetAsync(cb2, 0, NR_ * HD_ * sizeof(float), stream);
    k_deg<<<(EP_ + 255) / 256, 256, 0, stream>>>(ei, deg);
    k_scan<<<1, 1, 0, stream>>>(deg, rowptr, cursor);
    k_fill<<<(EP_ + 255) / 256, 256, 0, stream>>>(ei, cursor, eids);

    // ---- GAT1 ----
    gemm128<<<dim3(C1_ / 128, 32000 / 128), 256, 0, stream>>>(x, gat1_Wl, xl1, 32000, C1_, FIN_, nullptr, nullptr);
    gemm128<<<dim3(C1_ / 128, 32000 / 128), 256, 0, stream>>>(x, gat1_Wr, xr1, 32000, C1_, FIN_, nullptr, nullptr);
    k_gat<2, HD_><<<G_ * NN_, C1_, 0, stream>>>(xl1, xr1, gat1_att, ei, rowptr, eids, gat1_b, h1);
    k_bnstats<C1_><<<G_, C1_, 0, stream>>>(h1, mean1, rstd1);
    k_bn_elu<C1_><<<(G_ * NN_ * C1_ + 255) / 256, 256, 0, stream>>>(h1, mean1, rstd1, bn1_g, bn1_b);

    // ---- GAT2 ----
    gemm128<<<dim3(HD_ / 128, 32000 / 128), 256, 0, stream>>>(h1, gat2_Wl, xl2, 32000, HD_, C1_, nullptr, nullptr);
    gemm128<<<dim3(HD_ / 128, 32000 / 128), 256, 0, stream>>>(h1, gat2_Wr, xr2, 32000, HD_, C1_, nullptr, nullptr);
    k_gat<1, HD_><<<G_ * NN_, HD_, 0, stream>>>(xl2, xr2, gat2_att, ei, rowptr, eids, gat2_b, h2);
    k_bnstats<HD_><<<G_, HD_, 0, stream>>>(h2, mean2, rstd2);

    // ---- residual projection + BN2/ELU/add ----
    gemm128<<<dim3(HD_ / 128, 32000 / 128), 256, 0, stream>>>(x, W_proj, proj, 32000, HD_, FIN_, b_proj, nullptr);
    k_bn_elu_add<HD_><<<(G_ * NN_ * HD_ + 255) / 256, 256, 0, stream>>>(h2, mean2, rstd2, bn2_g, bn2_b, proj, hres);

    // ---- LSTM: layer1 step t runs concurrently with layer2 step t-1 ----
    // layer1 x-input: hres rows (r*16 + t) -> xin = hres + t*HD, row stride 16*HD
    // layer2 x-input: ys1[t-1], row stride HD
    for (int t = 0; t <= TT_; ++t) {
        int actA = (t < TT_) ? 1 : 0;
        int actB = (t >= 1) ? 1 : 0;
        int tt = t - 1;
        const float* hpA  = (t == 0) ? h0z : ys1 + (size_t)(t - 1) * NR_ * HD_;
        float*       hoA  = ys1 + (size_t)((t < TT_) ? t : 0) * NR_ * HD_;
        const float* xinA = hres + (size_t)((t < TT_) ? t : 0) * HD_;
        const float* hpB  = (tt <= 0) ? h0z : h2b;
        const float* xinB = ys1 + (size_t)((tt > 0) ? tt : 0) * NR_ * HD_;
        k_lstm_dual<<<250, 256, 0, stream>>>(
            hpA, Whh0, Wih0, xinA, (size_t)(TT_ * HD_), bih0, bhh0, cb1, hoA, actA,
            hpB, Whh1, Wih1, xinB, (size_t)HD_,        bih1, bhh1, cb2, h2b, actB);
    }

    // ---- FC head ----
    k_fc<<<NR_, 64, 0, stream>>>(h2b, fc_W1, fc_b1, fc_W2, fc_b2, out);
}